// Round 3
// baseline (2918.605 us; speedup 1.0000x reference)
//
#include <hip/hip_runtime.h>
#include <cstdint>
#include <cstddef>

#define WG 256
#define NB 16  // batch

// ---------------- small utility kernels ----------------

__global__ void k_zero_i(int* __restrict__ p, int n) {
  int i = blockIdx.x * WG + threadIdx.x;
  if (i < n) p[i] = 0;
}

__global__ void k_hist(const int* __restrict__ edges, int E,
                       int* __restrict__ dsrc, int* __restrict__ dtgt) {
  int e = blockIdx.x * WG + threadIdx.x;
  if (e >= E) return;
  atomicAdd(&dsrc[edges[e]], 1);
  atomicAdd(&dtgt[edges[E + e]], 1);
}

// single-workgroup exclusive scan of deg -> rowptr (N+1) and cursor copy
__global__ void k_scan(const int* __restrict__ deg, int N,
                       int* __restrict__ rowptr, int* __restrict__ cursor) {
  __shared__ int s[WG];
  int t = threadIdx.x;
  int chunk = (N + WG - 1) / WG;
  int a = t * chunk;
  int b = min(N, a + chunk);
  int sum = 0;
  for (int i = a; i < b; i++) sum += deg[i];
  s[t] = sum;
  __syncthreads();
  for (int off = 1; off < WG; off <<= 1) {
    int v = (t >= off) ? s[t - off] : 0;
    __syncthreads();
    s[t] += v;
    __syncthreads();
  }
  int run = (t == 0) ? 0 : s[t - 1];
  for (int i = a; i < b; i++) {
    rowptr[i] = run;
    cursor[i] = run;
    run += deg[i];
  }
  if (t == 0) rowptr[N] = s[WG - 1];
}

// fill CSR (by tgt) with src id and sym-norm weight dinv[src]*dinv[tgt]
__global__ void k_fill(const int* __restrict__ edges, int E,
                       const int* __restrict__ dsrc, int* __restrict__ cursor,
                       int* __restrict__ csrc, float* __restrict__ csw) {
  int e = blockIdx.x * WG + threadIdx.x;
  if (e >= E) return;
  int s = edges[e], t = edges[E + e];
  float da = (float)dsrc[s], db = (float)dsrc[t];
  float wa = (da > 0.f) ? (1.0f / sqrtf(da)) : 0.f;
  float wb = (db > 0.f) ? (1.0f / sqrtf(db)) : 0.f;
  int pos = atomicAdd(&cursor[t], 1);
  csrc[pos] = s;
  csw[pos] = wa * wb;
}

// ---------------- threefry eps = jax.random.normal(key(42),(16,64)) ----------------
// JAX >= 0.4.36 default: jax_threefry_partitionable=True
//   (b1, b2) = threefry2x32(key=(0,42), x=(hi32(i)=0, lo32(i)=i))
//   bits[i] = b1 ^ b2            // prng.py: bit_width in {8,16,32} path

static __device__ __forceinline__ float erfinv_f(float x) {
  float w = -log1pf(-x * x);
  float p;
  if (w < 5.0f) {
    w -= 2.5f;
    p = 2.81022636e-08f;
    p = fmaf(p, w, 3.43273939e-07f);
    p = fmaf(p, w, -3.5233877e-06f);
    p = fmaf(p, w, -4.39150654e-06f);
    p = fmaf(p, w, 0.00021858087f);
    p = fmaf(p, w, -0.00125372503f);
    p = fmaf(p, w, -0.00417768164f);
    p = fmaf(p, w, 0.246640727f);
    p = fmaf(p, w, 1.50140941f);
  } else {
    w = sqrtf(w) - 3.0f;
    p = -0.000200214257f;
    p = fmaf(p, w, 0.000100950558f);
    p = fmaf(p, w, 0.00134934322f);
    p = fmaf(p, w, -0.00367342844f);
    p = fmaf(p, w, 0.00573950773f);
    p = fmaf(p, w, -0.0076224613f);
    p = fmaf(p, w, 0.00943887047f);
    p = fmaf(p, w, 1.00167406f);
    p = fmaf(p, w, 2.83297682f);
  }
  return p * x;
}

static __device__ __forceinline__ float bits_to_normal(unsigned b) {
  float f = __uint_as_float((b >> 9) | 0x3f800000u) - 1.0f;  // [0,1)
  const float lo = -0.99999994f;                             // nextafter(-1,0)
  float u = f * (1.0f - lo) + lo;
  u = fmaxf(u, lo);
  return 1.41421356f * erfinv_f(u);
}

__global__ void k_eps(float* __restrict__ eps) {
  int i = blockIdx.x * WG + threadIdx.x;
  if (i >= 1024) return;
  unsigned x0 = 0u, x1 = (unsigned)i;  // (hi32(i), lo32(i)) for i < 2^32
  unsigned ks[3] = {0u, 42u, 0u ^ 42u ^ 0x1BD11BDAu};
  x0 += ks[0];
  x1 += ks[1];
  const int R[2][4] = {{13, 15, 26, 6}, {17, 29, 16, 24}};
#pragma unroll
  for (int it = 0; it < 5; it++) {
#pragma unroll
    for (int j = 0; j < 4; j++) {
      x0 += x1;
      int r = R[it & 1][j];
      x1 = (x1 << r) | (x1 >> (32 - r));
      x1 ^= x0;
    }
    x0 += ks[(it + 1) % 3];
    x1 += ks[(it + 2) % 3] + (unsigned)(it + 1);
  }
  eps[i] = bits_to_normal(x0 ^ x1);  // partitionable 32-bit combine
}

// ---------------- Chebyshev building blocks ----------------

// out = scale * (CSR-gather of in) - sub   (sub may be null)
// linear index == (b*N + n)*F + f layout
template <int F>
__global__ __launch_bounds__(WG) void k_prop(const float* __restrict__ in,
                                             float* __restrict__ out,
                                             const float* __restrict__ sub, float scale,
                                             const int* __restrict__ rowptr,
                                             const int* __restrict__ csrc,
                                             const float* __restrict__ csw, int N) {
  int idx = blockIdx.x * WG + threadIdx.x;
  int total = NB * N * F;
  if (idx >= total) return;
  int f = idx % F;
  int n = (idx / F) % N;
  int b = idx / (F * N);
  int beg = rowptr[n], end = rowptr[n + 1];
  const float* inb = in + (size_t)b * N * F + f;
  float acc = 0.f;
  for (int j = beg; j < end; j++) acc = fmaf(csw[j], inb[(size_t)csrc[j] * F], acc);
  float r = scale * acc;
  if (sub) r -= sub[idx];
  out[idx] = r;
}

// out (rows x G) (+)= Tx (rows x F) @ W (F x G); optional bias init, optional relu
template <int F, int G>
__global__ __launch_bounds__(WG) void k_gemm(const float* __restrict__ Tx,
                                             const float* __restrict__ W,
                                             const float* __restrict__ bias,
                                             float* __restrict__ out, int rows,
                                             int accum, int relu) {
  __shared__ float sW[F * G];
  for (int i = threadIdx.x; i < F * G; i += WG) sW[i] = W[i];
  __syncthreads();
  int row = blockIdx.x * WG + threadIdx.x;
  if (row >= rows) return;
  const float* t = Tx + (size_t)row * F;
  float x[F];
  if constexpr ((F & 3) == 0) {
#pragma unroll
    for (int f = 0; f < F; f += 4) {
      float4 v = *(const float4*)(t + f);
      x[f] = v.x; x[f + 1] = v.y; x[f + 2] = v.z; x[f + 3] = v.w;
    }
  } else {
#pragma unroll
    for (int f = 0; f < F; f++) x[f] = t[f];
  }
  float acc[G];
  float* o = out + (size_t)row * G;
  if (accum) {
    if constexpr ((G & 3) == 0) {
#pragma unroll
      for (int g = 0; g < G; g += 4) {
        float4 v = *(const float4*)(o + g);
        acc[g] = v.x; acc[g + 1] = v.y; acc[g + 2] = v.z; acc[g + 3] = v.w;
      }
    } else {
#pragma unroll
      for (int g = 0; g < G; g++) acc[g] = o[g];
    }
  } else if (bias) {
#pragma unroll
    for (int g = 0; g < G; g++) acc[g] = bias[g];
  } else {
#pragma unroll
    for (int g = 0; g < G; g++) acc[g] = 0.f;
  }
#pragma unroll
  for (int f = 0; f < F; f++) {
    float xf = x[f];
#pragma unroll
    for (int g = 0; g < G; g++) acc[g] = fmaf(xf, sW[f * G + g], acc[g]);
  }
  if (relu) {
#pragma unroll
    for (int g = 0; g < G; g++) acc[g] = fmaxf(acc[g], 0.f);
  }
  if constexpr ((G & 3) == 0) {
#pragma unroll
    for (int g = 0; g < G; g += 4) {
      float4 v;
      v.x = acc[g]; v.y = acc[g + 1]; v.z = acc[g + 2]; v.w = acc[g + 3];
      *(float4*)(o + g) = v;
    }
  } else {
#pragma unroll
    for (int g = 0; g < G; g++) o[g] = acc[g];
  }
}

// downsample gather with relu: out[(b*Nout+j)*F+f] = relu(in[(b*Nin+idx[j])*F+f])
template <int F>
__global__ __launch_bounds__(WG) void k_ds(const float* __restrict__ in,
                                           float* __restrict__ out,
                                           const int* __restrict__ idx, int Nin, int Nout) {
  int i = blockIdx.x * WG + threadIdx.x;
  int total = NB * Nout * F;
  if (i >= total) return;
  int f = i % F;
  int j = (i / F) % Nout;
  int b = i / (F * Nout);
  float v = in[((size_t)b * Nin + idx[j]) * F + f];
  out[i] = fmaxf(v, 0.f);
}

// upsample: out[(b*Nf+r)*F+f] = sum_k w[r,k]*relu(in[(b*Nc+uidx[r,k])*F+f])
// (relu fused here: every upsample input is relu(prev) in the reference)
template <int F>
__global__ __launch_bounds__(WG) void k_us(const float* __restrict__ in,
                                           float* __restrict__ out,
                                           const int* __restrict__ uidx,
                                           const float* __restrict__ uw, int Nc, int Nf) {
  int i = blockIdx.x * WG + threadIdx.x;
  int total = NB * Nf * F;
  if (i >= total) return;
  int f = i % F;
  int r = (i / F) % Nf;
  int b = i / (F * Nf);
  float acc = 0.f;
#pragma unroll
  for (int k = 0; k < 3; k++) {
    float v = in[((size_t)b * Nc + uidx[r * 3 + k]) * F + f];
    acc = fmaf(uw[r * 3 + k], fmaxf(v, 0.f), acc);
  }
  out[i] = acc;
}

// ---------------- latent kernels ----------------

// one wave per (b,g): mu/logvar dots over 5056, writes mu/lv to d_out, z+label into hcat
__global__ __launch_bounds__(64) void k_latent(const float* __restrict__ h,
                                               const float* __restrict__ muW,
                                               const float* __restrict__ muB,
                                               const float* __restrict__ lvW,
                                               const float* __restrict__ lvB,
                                               const float* __restrict__ eps,
                                               const float* __restrict__ label,
                                               float* __restrict__ mu_out,
                                               float* __restrict__ lv_out,
                                               float* __restrict__ hcat) {
  int b = blockIdx.x / 64;
  int g = blockIdx.x % 64;
  int l = threadIdx.x;
  const float* hb = h + (size_t)b * 5056;
  float am = 0.f, al = 0.f;
  for (int i = l; i < 5056; i += 64) {
    float hv = hb[i];
    am = fmaf(hv, muW[(size_t)i * 64 + g], am);
    al = fmaf(hv, lvW[(size_t)i * 64 + g], al);
  }
  for (int off = 32; off > 0; off >>= 1) {
    am += __shfl_down(am, off, 64);
    al += __shfl_down(al, off, 64);
  }
  if (l == 0) {
    am += muB[g];
    al += lvB[g];
    mu_out[b * 64 + g] = am;
    lv_out[b * 64 + g] = al;
    hcat[b * 66 + g] = fmaf(eps[b * 64 + g], expf(0.5f * al), am);
    if (g < 2) hcat[b * 66 + 64 + g] = label[b * 2 + g];
  }
}

__global__ __launch_bounds__(WG) void k_declin(const float* __restrict__ hcat,
                                               const float* __restrict__ W,
                                               const float* __restrict__ bias,
                                               float* __restrict__ out) {
  int idx = blockIdx.x * WG + threadIdx.x;
  if (idx >= NB * 5056) return;
  int b = idx / 5056, j = idx % 5056;
  float acc = bias[j];
  const float* hc = hcat + b * 66;
#pragma unroll
  for (int i = 0; i < 66; i++) acc = fmaf(hc[i], W[(size_t)i * 5056 + j], acc);
  out[idx] = fmaxf(acc, 0.f);
}

// ---------------- host orchestration ----------------

static inline dim3 grid1(long n) { return dim3((unsigned)((n + WG - 1) / WG)); }

// full K=6 Chebyshev layer: out = sum_k Tx_k @ W_k (+bias), optional final relu.
// Buffers: in (Tx0, read-only until prop #3), A, Bb rotate, Cc may alias `in`.
template <int F, int G>
static void run_cheb(const float* in, float* out, float* A, float* Bb, float* Cc,
                     const float* W, const float* bias, int N, int relu_last,
                     const int* rowptr, const int* csrc, const float* csw,
                     hipStream_t st) {
  int rows = NB * N;
  long total = (long)rows * F;
  dim3 gG = grid1(rows), gP = grid1(total);
  k_gemm<F, G><<<gG, WG, 0, st>>>(in, W, bias, out, rows, 0, 0);                     // T0
  k_prop<F><<<gP, WG, 0, st>>>(in, A, nullptr, 1.f, rowptr, csrc, csw, N);           // T1
  k_gemm<F, G><<<gG, WG, 0, st>>>(A, W + 1 * F * G, nullptr, out, rows, 1, 0);
  k_prop<F><<<gP, WG, 0, st>>>(A, Bb, in, 2.f, rowptr, csrc, csw, N);                // T2
  k_gemm<F, G><<<gG, WG, 0, st>>>(Bb, W + 2 * F * G, nullptr, out, rows, 1, 0);
  k_prop<F><<<gP, WG, 0, st>>>(Bb, Cc, A, 2.f, rowptr, csrc, csw, N);                // T3
  k_gemm<F, G><<<gG, WG, 0, st>>>(Cc, W + 3 * F * G, nullptr, out, rows, 1, 0);
  k_prop<F><<<gP, WG, 0, st>>>(Cc, A, Bb, 2.f, rowptr, csrc, csw, N);                // T4
  k_gemm<F, G><<<gG, WG, 0, st>>>(A, W + 4 * F * G, nullptr, out, rows, 1, 0);
  k_prop<F><<<gP, WG, 0, st>>>(A, Bb, Cc, 2.f, rowptr, csrc, csw, N);                // T5
  k_gemm<F, G><<<gG, WG, 0, st>>>(Bb, W + 5 * F * G, nullptr, out, rows, 1, relu_last);
}

extern "C" void kernel_launch(void* const* d_in, const int* in_sizes, int n_in,
                              void* d_out, int out_size, void* d_ws, size_t ws_size,
                              hipStream_t stream) {
  static const int NN[5] = {20000, 5000, 1250, 313, 79};
  static const int EE[5] = {120000, 30000, 7500, 1878, 474};
  static const int NCSR[5] = {20000, 5000, 1250, 313, 20000};  // level 4 CSR spans full array

  // ---- inputs ----
  const float* x = (const float*)d_in[0];
  const float* label = (const float*)d_in[1];
  const int* edges[5];
  for (int l = 0; l < 5; l++) edges[l] = (const int*)d_in[2 + l];
  const int* ds_idx[4];
  const int* us_idx[4];
  const float* us_w[4];
  for (int i = 0; i < 4; i++) {
    ds_idx[i] = (const int*)d_in[7 + 3 * i];
    us_idx[i] = (const int*)d_in[8 + 3 * i];
    us_w[i] = (const float*)d_in[9 + 3 * i];
  }
  const float* enc_w[4];
  const float* enc_b[4];
  for (int i = 0; i < 4; i++) {
    enc_w[i] = (const float*)d_in[19 + 2 * i];
    enc_b[i] = (const float*)d_in[20 + 2 * i];
  }
  const float* dec_w[5];
  for (int i = 0; i < 5; i++) dec_w[i] = (const float*)d_in[27 + i];
  const float* dec_b[4];
  for (int i = 0; i < 4; i++) dec_b[i] = (const float*)d_in[32 + i];
  const float* mu_w = (const float*)d_in[36];
  const float* mu_b = (const float*)d_in[37];
  const float* lv_w = (const float*)d_in[38];
  const float* lv_b = (const float*)d_in[39];
  const float* dl_w = (const float*)d_in[40];
  const float* dl_b = (const float*)d_in[41];

  // ---- workspace carve (floats, 256B aligned chunks) ----
  float* wsf = (float*)d_ws;
  size_t off = 0;
  auto carve = [&](size_t n) -> float* {
    float* p = wsf + off;
    off += (n + 63) & ~(size_t)63;
    return p;
  };
  const size_t SLOT = 10240000;  // 16*20000*32
  float* s0 = carve(SLOT);
  float* s1 = carve(SLOT);
  float* s2 = carve(SLOT);
  float* s3 = carve(SLOT);
  float* sc0 = carve(960000);  // enc0's third Tx buffer (F=3)
  int* deg_all = (int*)carve(26642 + 46563);
  int* deg_src_all = deg_all;
  int* deg_tgt_all = deg_all + 26642;
  int* rowptr_all = (int*)carve(46568);
  int* cursor_all = (int*)carve(46563);
  int* csrc_all = (int*)carve(159852);
  float* csw_all = carve(159852);
  float* eps = carve(1024);
  float* hcat = carve(1056);

  int NOFF[5], COFF[5], ROFF[5], EOFF[5];
  {
    int na = 0, ca = 0, ra = 0, ea = 0;
    for (int l = 0; l < 5; l++) {
      NOFF[l] = na; na += NN[l];
      COFF[l] = ca; ca += NCSR[l];
      ROFF[l] = ra; ra += NCSR[l] + 1;
      EOFF[l] = ea; ea += EE[l];
    }
  }

  // ---- norms + CSR build ----
  k_zero_i<<<grid1(26642 + 46563), WG, 0, stream>>>(deg_all, 26642 + 46563);
  for (int l = 0; l < 5; l++)
    k_hist<<<grid1(EE[l]), WG, 0, stream>>>(edges[l], EE[l], deg_src_all + NOFF[l],
                                            deg_tgt_all + COFF[l]);
  for (int l = 0; l < 5; l++)
    k_scan<<<1, WG, 0, stream>>>(deg_tgt_all + COFF[l], NCSR[l], rowptr_all + ROFF[l],
                                 cursor_all + COFF[l]);
  for (int l = 0; l < 5; l++)
    k_fill<<<grid1(EE[l]), WG, 0, stream>>>(edges[l], EE[l], deg_src_all + NOFF[l],
                                            cursor_all + COFF[l], csrc_all + EOFF[l],
                                            csw_all + EOFF[l]);
  k_eps<<<4, WG, 0, stream>>>(eps);

  auto RP = [&](int l) { return rowptr_all + ROFF[l]; };
  auto CS = [&](int l) { return csrc_all + EOFF[l]; };
  auto CW = [&](int l) { return csw_all + EOFF[l]; };

  // ---- encoder ----
  run_cheb<3, 32>(x, s0, s1, s2, sc0, enc_w[0], enc_b[0], 20000, 0, RP(0), CS(0), CW(0), stream);
  k_ds<32><<<grid1((long)NB * 5000 * 32), WG, 0, stream>>>(s0, s3, ds_idx[0], 20000, 5000);
  run_cheb<32, 32>(s3, s0, s1, s2, s3, enc_w[1], enc_b[1], 5000, 0, RP(1), CS(1), CW(1), stream);
  k_ds<32><<<grid1((long)NB * 1250 * 32), WG, 0, stream>>>(s0, s3, ds_idx[1], 5000, 1250);
  run_cheb<32, 64>(s3, s0, s1, s2, s3, enc_w[2], enc_b[2], 1250, 0, RP(2), CS(2), CW(2), stream);
  k_ds<64><<<grid1((long)NB * 313 * 64), WG, 0, stream>>>(s0, s3, ds_idx[2], 1250, 313);
  run_cheb<64, 64>(s3, s0, s1, s2, s3, enc_w[3], enc_b[3], 313, 0, RP(3), CS(3), CW(3), stream);
  k_ds<64><<<grid1((long)NB * 79 * 64), WG, 0, stream>>>(s0, s3, ds_idx[3], 313, 79);

  // ---- latent ----
  float* mu_out = (float*)d_out + 960000;
  float* lv_out = (float*)d_out + 961024;
  k_latent<<<1024, 64, 0, stream>>>(s3, mu_w, mu_b, lv_w, lv_b, eps, label, mu_out, lv_out, hcat);
  k_declin<<<grid1(NB * 5056), WG, 0, stream>>>(hcat, dl_w, dl_b, s3);

  // ---- decoder ----
  k_us<64><<<grid1((long)NB * 313 * 64), WG, 0, stream>>>(s3, s1, us_idx[3], us_w[3], 79, 313);
  run_cheb<64, 64>(s1, s0, s2, s3, s1, dec_w[0], dec_b[0], 313, 0, RP(3), CS(3), CW(3), stream);
  k_us<64><<<grid1((long)NB * 1250 * 64), WG, 0, stream>>>(s0, s1, us_idx[2], us_w[2], 313, 1250);
  run_cheb<64, 64>(s1, s0, s2, s3, s1, dec_w[1], dec_b[1], 1250, 0, RP(2), CS(2), CW(2), stream);
  k_us<64><<<grid1((long)NB * 5000 * 64), WG, 0, stream>>>(s0, s1, us_idx[1], us_w[1], 1250, 5000);
  run_cheb<64, 32>(s1, s0, s2, s3, s1, dec_w[2], dec_b[2], 5000, 0, RP(1), CS(1), CW(1), stream);
  k_us<32><<<grid1((long)NB * 20000 * 32), WG, 0, stream>>>(s0, s1, us_idx[0], us_w[0], 5000, 20000);
  run_cheb<32, 32>(s1, s0, s2, s3, s1, dec_w[3], dec_b[3], 20000, 1, RP(0), CS(0), CW(0), stream);
  // final cheb: 79-node graph applied to the 20000-node array, no bias/relu, straight to d_out
  run_cheb<32, 3>(s0, (float*)d_out, s1, s2, s0, dec_w[4], nullptr, 20000, 0, RP(4), CS(4), CW(4), stream);
}

// Round 4
// 2796.565 us; speedup vs baseline: 1.0436x; 1.0436x over previous
//
#include <hip/hip_runtime.h>
#include <cstdint>
#include <cstddef>

#define WG 256
#define NB 16  // batch

// ---------------- small utility kernels ----------------

__global__ void k_zero_i(int* __restrict__ p, int n) {
  int i = blockIdx.x * WG + threadIdx.x;
  if (i < n) p[i] = 0;
}

__global__ void k_hist(const int* __restrict__ edges, int E,
                       int* __restrict__ dsrc, int* __restrict__ dtgt) {
  int e = blockIdx.x * WG + threadIdx.x;
  if (e >= E) return;
  atomicAdd(&dsrc[edges[e]], 1);
  atomicAdd(&dtgt[edges[E + e]], 1);
}

// single-workgroup exclusive scan of deg -> rowptr (N+1) and cursor copy
__global__ void k_scan(const int* __restrict__ deg, int N,
                       int* __restrict__ rowptr, int* __restrict__ cursor) {
  __shared__ int s[WG];
  int t = threadIdx.x;
  int chunk = (N + WG - 1) / WG;
  int a = t * chunk;
  int b = min(N, a + chunk);
  int sum = 0;
  for (int i = a; i < b; i++) sum += deg[i];
  s[t] = sum;
  __syncthreads();
  for (int off = 1; off < WG; off <<= 1) {
    int v = (t >= off) ? s[t - off] : 0;
    __syncthreads();
    s[t] += v;
    __syncthreads();
  }
  int run = (t == 0) ? 0 : s[t - 1];
  for (int i = a; i < b; i++) {
    rowptr[i] = run;
    cursor[i] = run;
    run += deg[i];
  }
  if (t == 0) rowptr[N] = s[WG - 1];
}

// fill CSR (by tgt) with src id and sym-norm weight dinv[src]*dinv[tgt]
__global__ void k_fill(const int* __restrict__ edges, int E,
                       const int* __restrict__ dsrc, int* __restrict__ cursor,
                       int* __restrict__ csrc, float* __restrict__ csw) {
  int e = blockIdx.x * WG + threadIdx.x;
  if (e >= E) return;
  int s = edges[e], t = edges[E + e];
  float da = (float)dsrc[s], db = (float)dsrc[t];
  float wa = (da > 0.f) ? (1.0f / sqrtf(da)) : 0.f;
  float wb = (db > 0.f) ? (1.0f / sqrtf(db)) : 0.f;
  int pos = atomicAdd(&cursor[t], 1);
  csrc[pos] = s;
  csw[pos] = wa * wb;
}

// ---------------- threefry eps = jax.random.normal(key(42),(16,64)) ----------------
// JAX >= 0.4.36 partitionable path: bits[i] = b1 ^ b2 of
// threefry2x32(key=(0,42), x=(0, i))   [verified: passes vs harness JAX ref]

static __device__ __forceinline__ float erfinv_f(float x) {
  float w = -log1pf(-x * x);
  float p;
  if (w < 5.0f) {
    w -= 2.5f;
    p = 2.81022636e-08f;
    p = fmaf(p, w, 3.43273939e-07f);
    p = fmaf(p, w, -3.5233877e-06f);
    p = fmaf(p, w, -4.39150654e-06f);
    p = fmaf(p, w, 0.00021858087f);
    p = fmaf(p, w, -0.00125372503f);
    p = fmaf(p, w, -0.00417768164f);
    p = fmaf(p, w, 0.246640727f);
    p = fmaf(p, w, 1.50140941f);
  } else {
    w = sqrtf(w) - 3.0f;
    p = -0.000200214257f;
    p = fmaf(p, w, 0.000100950558f);
    p = fmaf(p, w, 0.00134934322f);
    p = fmaf(p, w, -0.00367342844f);
    p = fmaf(p, w, 0.00573950773f);
    p = fmaf(p, w, -0.0076224613f);
    p = fmaf(p, w, 0.00943887047f);
    p = fmaf(p, w, 1.00167406f);
    p = fmaf(p, w, 2.83297682f);
  }
  return p * x;
}

static __device__ __forceinline__ float bits_to_normal(unsigned b) {
  float f = __uint_as_float((b >> 9) | 0x3f800000u) - 1.0f;  // [0,1)
  const float lo = -0.99999994f;                             // nextafter(-1,0)
  float u = f * (1.0f - lo) + lo;
  u = fmaxf(u, lo);
  return 1.41421356f * erfinv_f(u);
}

__global__ void k_eps(float* __restrict__ eps) {
  int i = blockIdx.x * WG + threadIdx.x;
  if (i >= 1024) return;
  unsigned x0 = 0u, x1 = (unsigned)i;
  unsigned ks[3] = {0u, 42u, 0u ^ 42u ^ 0x1BD11BDAu};
  x0 += ks[0];
  x1 += ks[1];
  const int R[2][4] = {{13, 15, 26, 6}, {17, 29, 16, 24}};
#pragma unroll
  for (int it = 0; it < 5; it++) {
#pragma unroll
    for (int j = 0; j < 4; j++) {
      x0 += x1;
      int r = R[it & 1][j];
      x1 = (x1 << r) | (x1 >> (32 - r));
      x1 ^= x0;
    }
    x0 += ks[(it + 1) % 3];
    x1 += ks[(it + 2) % 3] + (unsigned)(it + 1);
  }
  eps[i] = bits_to_normal(x0 ^ x1);
}

// ---------------- Chebyshev building blocks ----------------

// out = scale * (CSR-gather of in) - sub   (sub may be null)
template <int F>
__global__ __launch_bounds__(WG) void k_prop(const float* __restrict__ in,
                                             float* __restrict__ out,
                                             const float* __restrict__ sub, float scale,
                                             const int* __restrict__ rowptr,
                                             const int* __restrict__ csrc,
                                             const float* __restrict__ csw, int N) {
  int idx = blockIdx.x * WG + threadIdx.x;
  int total = NB * N * F;
  if (idx >= total) return;
  int f = idx % F;
  int n = (idx / F) % N;
  int b = idx / (F * N);
  int beg = rowptr[n], end = rowptr[n + 1];
  const float* inb = in + (size_t)b * N * F + f;
  float acc = 0.f;
  for (int j = beg; j < end; j++) acc = fmaf(csw[j], inb[(size_t)csrc[j] * F], acc);
  float r = scale * acc;
  if (sub) r -= sub[idx];
  out[idx] = r;
}

// ---- fused all-K GEMM: out = sum_kk txs[kk] @ W[kk] (+bias / +accum), opt relu
struct Ptr6 {
  const float* p[6];
};

template <int F, int G, int KC>
__global__ __launch_bounds__(WG) void k_gemm6(Ptr6 txs, const float* __restrict__ W,
                                              const float* __restrict__ bias,
                                              float* __restrict__ out, int rows,
                                              int accum, int relu) {
  __shared__ float sW[KC * F * G];
  for (int i = threadIdx.x; i < KC * F * G; i += WG) sW[i] = W[i];
  __syncthreads();
  int row = blockIdx.x * WG + threadIdx.x;
  if (row >= rows) return;
  float acc[G];
  float* o = out + (size_t)row * G;
  if (accum) {
    if constexpr ((G & 3) == 0) {
#pragma unroll
      for (int g = 0; g < G; g += 4) {
        float4 v = *(const float4*)(o + g);
        acc[g] = v.x; acc[g + 1] = v.y; acc[g + 2] = v.z; acc[g + 3] = v.w;
      }
    } else {
#pragma unroll
      for (int g = 0; g < G; g++) acc[g] = o[g];
    }
  } else if (bias) {
#pragma unroll
    for (int g = 0; g < G; g++) acc[g] = bias[g];
  } else {
#pragma unroll
    for (int g = 0; g < G; g++) acc[g] = 0.f;
  }
#pragma unroll
  for (int kk = 0; kk < KC; kk++) {
    const float* t = txs.p[kk] + (size_t)row * F;
    float x[F];
    if constexpr ((F & 3) == 0) {
#pragma unroll
      for (int f = 0; f < F; f += 4) {
        float4 v = *(const float4*)(t + f);
        x[f] = v.x; x[f + 1] = v.y; x[f + 2] = v.z; x[f + 3] = v.w;
      }
    } else {
#pragma unroll
      for (int f = 0; f < F; f++) x[f] = t[f];
    }
    const float* w = sW + kk * F * G;
#pragma unroll
    for (int f = 0; f < F; f++) {
      float xf = x[f];
#pragma unroll
      for (int g = 0; g < G; g++) acc[g] = fmaf(xf, w[f * G + g], acc[g]);
    }
  }
  if (relu) {
#pragma unroll
    for (int g = 0; g < G; g++) acc[g] = fmaxf(acc[g], 0.f);
  }
  if constexpr ((G & 3) == 0) {
#pragma unroll
    for (int g = 0; g < G; g += 4) {
      float4 v;
      v.x = acc[g]; v.y = acc[g + 1]; v.z = acc[g + 2]; v.w = acc[g + 3];
      *(float4*)(o + g) = v;
    }
  } else {
#pragma unroll
    for (int g = 0; g < G; g++) o[g] = acc[g];
  }
}

// legacy sequential gemm (fallback path)
template <int F, int G>
__global__ __launch_bounds__(WG) void k_gemm(const float* __restrict__ Tx,
                                             const float* __restrict__ W,
                                             const float* __restrict__ bias,
                                             float* __restrict__ out, int rows,
                                             int accum, int relu) {
  __shared__ float sW[F * G];
  for (int i = threadIdx.x; i < F * G; i += WG) sW[i] = W[i];
  __syncthreads();
  int row = blockIdx.x * WG + threadIdx.x;
  if (row >= rows) return;
  const float* t = Tx + (size_t)row * F;
  float x[F];
#pragma unroll
  for (int f = 0; f < F; f++) x[f] = t[f];
  float acc[G];
  float* o = out + (size_t)row * G;
  if (accum) {
#pragma unroll
    for (int g = 0; g < G; g++) acc[g] = o[g];
  } else if (bias) {
#pragma unroll
    for (int g = 0; g < G; g++) acc[g] = bias[g];
  } else {
#pragma unroll
    for (int g = 0; g < G; g++) acc[g] = 0.f;
  }
#pragma unroll
  for (int f = 0; f < F; f++) {
    float xf = x[f];
#pragma unroll
    for (int g = 0; g < G; g++) acc[g] = fmaf(xf, sW[f * G + g], acc[g]);
  }
  if (relu) {
#pragma unroll
    for (int g = 0; g < G; g++) acc[g] = fmaxf(acc[g], 0.f);
  }
#pragma unroll
  for (int g = 0; g < G; g++) o[g] = acc[g];
}

// ---- final level-4 cheb shortcut ----
// rows n>=79 of the 79-node graph: T1=T3=T5=0, T2=-T0, T4=T0
//   => out = T0 @ (W0 - W2 + W4).  Compute for ALL rows; fixup overwrites n<79.
__global__ __launch_bounds__(WG) void k_final_short(const float* __restrict__ in,
                                                    const float* __restrict__ W,  // 6x32x3
                                                    float* __restrict__ out, int rows) {
  __shared__ float sW[96];
  if (threadIdx.x < 96)
    sW[threadIdx.x] = W[threadIdx.x] - W[192 + threadIdx.x] + W[384 + threadIdx.x];
  __syncthreads();
  int row = blockIdx.x * WG + threadIdx.x;
  if (row >= rows) return;
  const float* t = in + (size_t)row * 32;
  float a0 = 0.f, a1 = 0.f, a2 = 0.f;
#pragma unroll
  for (int f = 0; f < 32; f += 4) {
    float4 v = *(const float4*)(t + f);
    a0 = fmaf(v.x, sW[(f + 0) * 3 + 0], a0); a1 = fmaf(v.x, sW[(f + 0) * 3 + 1], a1); a2 = fmaf(v.x, sW[(f + 0) * 3 + 2], a2);
    a0 = fmaf(v.y, sW[(f + 1) * 3 + 0], a0); a1 = fmaf(v.y, sW[(f + 1) * 3 + 1], a1); a2 = fmaf(v.y, sW[(f + 1) * 3 + 2], a2);
    a0 = fmaf(v.z, sW[(f + 2) * 3 + 0], a0); a1 = fmaf(v.z, sW[(f + 2) * 3 + 1], a1); a2 = fmaf(v.z, sW[(f + 2) * 3 + 2], a2);
    a0 = fmaf(v.w, sW[(f + 3) * 3 + 0], a0); a1 = fmaf(v.w, sW[(f + 3) * 3 + 1], a1); a2 = fmaf(v.w, sW[(f + 3) * 3 + 2], a2);
  }
  float* o = out + (size_t)row * 3;
  o[0] = a0; o[1] = a1; o[2] = a2;
}

// exact K=6 recurrence for the 79 real nodes, fully in LDS. 16 blocks (one per batch).
__global__ __launch_bounds__(256) void k_final_fix(const float* __restrict__ in,  // (b,20000,32)
                                                   const float* __restrict__ W,   // 6x32x3
                                                   const int* __restrict__ rowptr,
                                                   const int* __restrict__ csrc,
                                                   const float* __restrict__ csw,
                                                   float* __restrict__ out) {
  __shared__ float B0[79 * 32], B1[79 * 32], B2[79 * 32];
  __shared__ float sacc[79 * 3];
  __shared__ float sW[576];
  int b = blockIdx.x, t = threadIdx.x;
  for (int i = t; i < 576; i += 256) sW[i] = W[i];
  const float* inb = in + (size_t)b * 20000 * 32;
  for (int i = t; i < 2528; i += 256) B0[i] = inb[i];
  __syncthreads();
  // acc = T0*W0 ; B1 = T1 = prop(T0)
  for (int i = t; i < 237; i += 256) {
    int r = i / 3, g = i % 3;
    float a = 0.f;
    for (int f = 0; f < 32; f++) a = fmaf(B0[r * 32 + f], sW[f * 3 + g], a);
    sacc[i] = a;
  }
  for (int i = t; i < 2528; i += 256) {
    int r = i >> 5, f = i & 31;
    float a = 0.f;
    for (int j = rowptr[r]; j < rowptr[r + 1]; j++) a = fmaf(csw[j], B0[csrc[j] * 32 + f], a);
    B1[i] = a;
  }
  __syncthreads();
  // acc += T1*W1 ; B2 = T2 = 2 prop(T1) - T0
  for (int i = t; i < 237; i += 256) {
    int r = i / 3, g = i % 3;
    float a = sacc[i];
    for (int f = 0; f < 32; f++) a = fmaf(B1[r * 32 + f], sW[96 + f * 3 + g], a);
    sacc[i] = a;
  }
  for (int i = t; i < 2528; i += 256) {
    int r = i >> 5, f = i & 31;
    float a = 0.f;
    for (int j = rowptr[r]; j < rowptr[r + 1]; j++) a = fmaf(csw[j], B1[csrc[j] * 32 + f], a);
    B2[i] = 2.f * a - B0[i];
  }
  __syncthreads();
  // acc += T2*W2 ; B0 = T3 = 2 prop(T2) - T1
  for (int i = t; i < 237; i += 256) {
    int r = i / 3, g = i % 3;
    float a = sacc[i];
    for (int f = 0; f < 32; f++) a = fmaf(B2[r * 32 + f], sW[192 + f * 3 + g], a);
    sacc[i] = a;
  }
  __syncthreads();  // B0 reads (above none, but T3 write below reads B1) — guard B0 overwrite vs T2's "-B0" already done
  for (int i = t; i < 2528; i += 256) {
    int r = i >> 5, f = i & 31;
    float a = 0.f;
    for (int j = rowptr[r]; j < rowptr[r + 1]; j++) a = fmaf(csw[j], B2[csrc[j] * 32 + f], a);
    B0[i] = 2.f * a - B1[i];
  }
  __syncthreads();
  // acc += T3*W3 ; B1 = T4 = 2 prop(T3) - T2
  for (int i = t; i < 237; i += 256) {
    int r = i / 3, g = i % 3;
    float a = sacc[i];
    for (int f = 0; f < 32; f++) a = fmaf(B0[r * 32 + f], sW[288 + f * 3 + g], a);
    sacc[i] = a;
  }
  __syncthreads();
  for (int i = t; i < 2528; i += 256) {
    int r = i >> 5, f = i & 31;
    float a = 0.f;
    for (int j = rowptr[r]; j < rowptr[r + 1]; j++) a = fmaf(csw[j], B0[csrc[j] * 32 + f], a);
    B1[i] = 2.f * a - B2[i];
  }
  __syncthreads();
  // acc += T4*W4 ; B2 = T5 = 2 prop(T4) - T3
  for (int i = t; i < 237; i += 256) {
    int r = i / 3, g = i % 3;
    float a = sacc[i];
    for (int f = 0; f < 32; f++) a = fmaf(B1[r * 32 + f], sW[384 + f * 3 + g], a);
    sacc[i] = a;
  }
  __syncthreads();
  for (int i = t; i < 2528; i += 256) {
    int r = i >> 5, f = i & 31;
    float a = 0.f;
    for (int j = rowptr[r]; j < rowptr[r + 1]; j++) a = fmaf(csw[j], B1[csrc[j] * 32 + f], a);
    B2[i] = 2.f * a - B0[i];
  }
  __syncthreads();
  // acc += T5*W5 ; write out
  for (int i = t; i < 237; i += 256) {
    int r = i / 3, g = i % 3;
    float a = sacc[i];
    for (int f = 0; f < 32; f++) a = fmaf(B2[r * 32 + f], sW[480 + f * 3 + g], a);
    out[((size_t)b * 20000 + r) * 3 + g] = a;
  }
}

// downsample gather with relu
template <int F>
__global__ __launch_bounds__(WG) void k_ds(const float* __restrict__ in,
                                           float* __restrict__ out,
                                           const int* __restrict__ idx, int Nin, int Nout) {
  int i = blockIdx.x * WG + threadIdx.x;
  int total = NB * Nout * F;
  if (i >= total) return;
  int f = i % F;
  int j = (i / F) % Nout;
  int b = i / (F * Nout);
  float v = in[((size_t)b * Nin + idx[j]) * F + f];
  out[i] = fmaxf(v, 0.f);
}

// upsample with fused relu on input
template <int F>
__global__ __launch_bounds__(WG) void k_us(const float* __restrict__ in,
                                           float* __restrict__ out,
                                           const int* __restrict__ uidx,
                                           const float* __restrict__ uw, int Nc, int Nf) {
  int i = blockIdx.x * WG + threadIdx.x;
  int total = NB * Nf * F;
  if (i >= total) return;
  int f = i % F;
  int r = (i / F) % Nf;
  int b = i / (F * Nf);
  float acc = 0.f;
#pragma unroll
  for (int k = 0; k < 3; k++) {
    float v = in[((size_t)b * Nc + uidx[r * 3 + k]) * F + f];
    acc = fmaf(uw[r * 3 + k], fmaxf(v, 0.f), acc);
  }
  out[i] = acc;
}

// ---------------- latent kernels ----------------

__global__ __launch_bounds__(64) void k_latent(const float* __restrict__ h,
                                               const float* __restrict__ muW,
                                               const float* __restrict__ muB,
                                               const float* __restrict__ lvW,
                                               const float* __restrict__ lvB,
                                               const float* __restrict__ eps,
                                               const float* __restrict__ label,
                                               float* __restrict__ mu_out,
                                               float* __restrict__ lv_out,
                                               float* __restrict__ hcat) {
  int b = blockIdx.x / 64;
  int g = blockIdx.x % 64;
  int l = threadIdx.x;
  const float* hb = h + (size_t)b * 5056;
  float am = 0.f, al = 0.f;
  for (int i = l; i < 5056; i += 64) {
    float hv = hb[i];
    am = fmaf(hv, muW[(size_t)i * 64 + g], am);
    al = fmaf(hv, lvW[(size_t)i * 64 + g], al);
  }
  for (int off = 32; off > 0; off >>= 1) {
    am += __shfl_down(am, off, 64);
    al += __shfl_down(al, off, 64);
  }
  if (l == 0) {
    am += muB[g];
    al += lvB[g];
    mu_out[b * 64 + g] = am;
    lv_out[b * 64 + g] = al;
    hcat[b * 66 + g] = fmaf(eps[b * 64 + g], expf(0.5f * al), am);
    if (g < 2) hcat[b * 66 + 64 + g] = label[b * 2 + g];
  }
}

__global__ __launch_bounds__(WG) void k_declin(const float* __restrict__ hcat,
                                               const float* __restrict__ W,
                                               const float* __restrict__ bias,
                                               float* __restrict__ out) {
  int idx = blockIdx.x * WG + threadIdx.x;
  if (idx >= NB * 5056) return;
  int b = idx / 5056, j = idx % 5056;
  float acc = bias[j];
  const float* hc = hcat + b * 66;
#pragma unroll
  for (int i = 0; i < 66; i++) acc = fmaf(hc[i], W[(size_t)i * 5056 + j], acc);
  out[idx] = fmaxf(acc, 0.f);
}

// ---------------- host orchestration ----------------

static inline dim3 grid1(long n) { return dim3((unsigned)((n + WG - 1) / WG)); }

// fused-path cheb: 5 props into T[0..4] (=T1..T5), one (or two) gemm6 pass(es)
template <int F, int G>
static void run_cheb6(const float* in, float* out, float* const* T,
                      const float* W, const float* bias, int N, int relu_last,
                      const int* rowptr, const int* csrc, const float* csw,
                      hipStream_t st) {
  int rows = NB * N;
  long total = (long)rows * F;
  dim3 gG = grid1(rows), gP = grid1(total);
  k_prop<F><<<gP, WG, 0, st>>>(in, T[0], nullptr, 1.f, rowptr, csrc, csw, N);
  k_prop<F><<<gP, WG, 0, st>>>(T[0], T[1], in, 2.f, rowptr, csrc, csw, N);
  k_prop<F><<<gP, WG, 0, st>>>(T[1], T[2], T[0], 2.f, rowptr, csrc, csw, N);
  k_prop<F><<<gP, WG, 0, st>>>(T[2], T[3], T[1], 2.f, rowptr, csrc, csw, N);
  k_prop<F><<<gP, WG, 0, st>>>(T[3], T[4], T[2], 2.f, rowptr, csrc, csw, N);
  if constexpr (F * G <= 2730) {  // 6*F*G*4 <= 64KB LDS
    Ptr6 p{{in, T[0], T[1], T[2], T[3], T[4]}};
    k_gemm6<F, G, 6><<<gG, WG, 0, st>>>(p, W, bias, out, rows, 0, relu_last);
  } else {
    Ptr6 p1{{in, T[0], T[1], nullptr, nullptr, nullptr}};
    Ptr6 p2{{T[2], T[3], T[4], nullptr, nullptr, nullptr}};
    k_gemm6<F, G, 3><<<gG, WG, 0, st>>>(p1, W, bias, out, rows, 0, 0);
    k_gemm6<F, G, 3><<<gG, WG, 0, st>>>(p2, W + 3 * F * G, nullptr, out, rows, 1, relu_last);
  }
}

// legacy sequential cheb (fallback when ws too small for 7 slots)
template <int F, int G>
static void run_cheb(const float* in, float* out, float* A, float* Bb, float* Cc,
                     const float* W, const float* bias, int N, int relu_last,
                     const int* rowptr, const int* csrc, const float* csw,
                     hipStream_t st) {
  int rows = NB * N;
  long total = (long)rows * F;
  dim3 gG = grid1(rows), gP = grid1(total);
  k_gemm<F, G><<<gG, WG, 0, st>>>(in, W, bias, out, rows, 0, 0);
  k_prop<F><<<gP, WG, 0, st>>>(in, A, nullptr, 1.f, rowptr, csrc, csw, N);
  k_gemm<F, G><<<gG, WG, 0, st>>>(A, W + 1 * F * G, nullptr, out, rows, 1, 0);
  k_prop<F><<<gP, WG, 0, st>>>(A, Bb, in, 2.f, rowptr, csrc, csw, N);
  k_gemm<F, G><<<gG, WG, 0, st>>>(Bb, W + 2 * F * G, nullptr, out, rows, 1, 0);
  k_prop<F><<<gP, WG, 0, st>>>(Bb, Cc, A, 2.f, rowptr, csrc, csw, N);
  k_gemm<F, G><<<gG, WG, 0, st>>>(Cc, W + 3 * F * G, nullptr, out, rows, 1, 0);
  k_prop<F><<<gP, WG, 0, st>>>(Cc, A, Bb, 2.f, rowptr, csrc, csw, N);
  k_gemm<F, G><<<gG, WG, 0, st>>>(A, W + 4 * F * G, nullptr, out, rows, 1, 0);
  k_prop<F><<<gP, WG, 0, st>>>(A, Bb, Cc, 2.f, rowptr, csrc, csw, N);
  k_gemm<F, G><<<gG, WG, 0, st>>>(Bb, W + 5 * F * G, nullptr, out, rows, 1, relu_last);
}

extern "C" void kernel_launch(void* const* d_in, const int* in_sizes, int n_in,
                              void* d_out, int out_size, void* d_ws, size_t ws_size,
                              hipStream_t stream) {
  static const int NN[5] = {20000, 5000, 1250, 313, 79};
  static const int EE[5] = {120000, 30000, 7500, 1878, 474};
  static const int NCSR[5] = {20000, 5000, 1250, 313, 20000};

  // ---- inputs ----
  const float* x = (const float*)d_in[0];
  const float* label = (const float*)d_in[1];
  const int* edges[5];
  for (int l = 0; l < 5; l++) edges[l] = (const int*)d_in[2 + l];
  const int* ds_idx[4];
  const int* us_idx[4];
  const float* us_w[4];
  for (int i = 0; i < 4; i++) {
    ds_idx[i] = (const int*)d_in[7 + 3 * i];
    us_idx[i] = (const int*)d_in[8 + 3 * i];
    us_w[i] = (const float*)d_in[9 + 3 * i];
  }
  const float* enc_w[4];
  const float* enc_b[4];
  for (int i = 0; i < 4; i++) {
    enc_w[i] = (const float*)d_in[19 + 2 * i];
    enc_b[i] = (const float*)d_in[20 + 2 * i];
  }
  const float* dec_w[5];
  for (int i = 0; i < 5; i++) dec_w[i] = (const float*)d_in[27 + i];
  const float* dec_b[4];
  for (int i = 0; i < 4; i++) dec_b[i] = (const float*)d_in[32 + i];
  const float* mu_w = (const float*)d_in[36];
  const float* mu_b = (const float*)d_in[37];
  const float* lv_w = (const float*)d_in[38];
  const float* lv_b = (const float*)d_in[39];
  const float* dl_w = (const float*)d_in[40];
  const float* dl_b = (const float*)d_in[41];

  // ---- workspace carve ----
  float* wsf = (float*)d_ws;
  size_t off = 0;
  auto carve = [&](size_t n) -> float* {
    float* p = wsf + off;
    off += (n + 63) & ~(size_t)63;
    return p;
  };
  const size_t SLOT = 10240000;  // 16*20000*32 floats
  float* s0 = carve(SLOT);
  float* s1 = carve(SLOT);
  float* s2 = carve(SLOT);
  float* s3 = carve(SLOT);
  float* sc0 = carve(960000);
  int* deg_all = (int*)carve(26642 + 46563);
  int* deg_src_all = deg_all;
  int* deg_tgt_all = deg_all + 26642;
  int* rowptr_all = (int*)carve(46568);
  int* cursor_all = (int*)carve(46563);
  int* csrc_all = (int*)carve(159852);
  float* csw_all = carve(159852);
  float* eps = carve(1024);
  float* hcat = carve(1056);
  size_t base_need = off * 4;
  // fused-path extra Tx slots
  float* t4 = carve(SLOT);
  float* t5 = carve(SLOT);
  float* t6 = carve(SLOT);
  size_t fused_need = off * 4;
  bool fused = ws_size >= fused_need;
  (void)base_need;

  int NOFF[5], COFF[5], ROFF[5], EOFF[5];
  {
    int na = 0, ca = 0, ra = 0, ea = 0;
    for (int l = 0; l < 5; l++) {
      NOFF[l] = na; na += NN[l];
      COFF[l] = ca; ca += NCSR[l];
      ROFF[l] = ra; ra += NCSR[l] + 1;
      EOFF[l] = ea; ea += EE[l];
    }
  }

  // ---- norms + CSR build ----
  k_zero_i<<<grid1(26642 + 46563), WG, 0, stream>>>(deg_all, 26642 + 46563);
  for (int l = 0; l < 5; l++)
    k_hist<<<grid1(EE[l]), WG, 0, stream>>>(edges[l], EE[l], deg_src_all + NOFF[l],
                                            deg_tgt_all + COFF[l]);
  for (int l = 0; l < 5; l++)
    k_scan<<<1, WG, 0, stream>>>(deg_tgt_all + COFF[l], NCSR[l], rowptr_all + ROFF[l],
                                 cursor_all + COFF[l]);
  for (int l = 0; l < 5; l++)
    k_fill<<<grid1(EE[l]), WG, 0, stream>>>(edges[l], EE[l], deg_src_all + NOFF[l],
                                            cursor_all + COFF[l], csrc_all + EOFF[l],
                                            csw_all + EOFF[l]);
  k_eps<<<4, WG, 0, stream>>>(eps);

  auto RP = [&](int l) { return rowptr_all + ROFF[l]; };
  auto CS = [&](int l) { return csrc_all + EOFF[l]; };
  auto CW = [&](int l) { return csw_all + EOFF[l]; };

  float* mu_out = (float*)d_out + 960000;
  float* lv_out = (float*)d_out + 961024;

  if (fused) {
    float* T[5] = {s2, s3, t4, t5, t6};
    // ---- encoder ----
    run_cheb6<3, 32>(x, s0, T, enc_w[0], enc_b[0], 20000, 0, RP(0), CS(0), CW(0), stream);
    k_ds<32><<<grid1((long)NB * 5000 * 32), WG, 0, stream>>>(s0, s1, ds_idx[0], 20000, 5000);
    run_cheb6<32, 32>(s1, s0, T, enc_w[1], enc_b[1], 5000, 0, RP(1), CS(1), CW(1), stream);
    k_ds<32><<<grid1((long)NB * 1250 * 32), WG, 0, stream>>>(s0, s1, ds_idx[1], 5000, 1250);
    run_cheb6<32, 64>(s1, s0, T, enc_w[2], enc_b[2], 1250, 0, RP(2), CS(2), CW(2), stream);
    k_ds<64><<<grid1((long)NB * 313 * 64), WG, 0, stream>>>(s0, s1, ds_idx[2], 1250, 313);
    run_cheb6<64, 64>(s1, s0, T, enc_w[3], enc_b[3], 313, 0, RP(3), CS(3), CW(3), stream);
    k_ds<64><<<grid1((long)NB * 79 * 64), WG, 0, stream>>>(s0, s1, ds_idx[3], 313, 79);
    // ---- latent ----
    k_latent<<<1024, 64, 0, stream>>>(s1, mu_w, mu_b, lv_w, lv_b, eps, label, mu_out, lv_out, hcat);
    k_declin<<<grid1(NB * 5056), WG, 0, stream>>>(hcat, dl_w, dl_b, s0);
    // ---- decoder ----
    k_us<64><<<grid1((long)NB * 313 * 64), WG, 0, stream>>>(s0, s1, us_idx[3], us_w[3], 79, 313);
    run_cheb6<64, 64>(s1, s0, T, dec_w[0], dec_b[0], 313, 0, RP(3), CS(3), CW(3), stream);
    k_us<64><<<grid1((long)NB * 1250 * 64), WG, 0, stream>>>(s0, s1, us_idx[2], us_w[2], 313, 1250);
    run_cheb6<64, 64>(s1, s0, T, dec_w[1], dec_b[1], 1250, 0, RP(2), CS(2), CW(2), stream);
    k_us<64><<<grid1((long)NB * 5000 * 64), WG, 0, stream>>>(s0, s1, us_idx[1], us_w[1], 1250, 5000);
    run_cheb6<64, 32>(s1, s0, T, dec_w[2], dec_b[2], 5000, 0, RP(1), CS(1), CW(1), stream);
    k_us<32><<<grid1((long)NB * 20000 * 32), WG, 0, stream>>>(s0, s1, us_idx[0], us_w[0], 5000, 20000);
    run_cheb6<32, 32>(s1, s0, T, dec_w[3], dec_b[3], 20000, 1, RP(0), CS(0), CW(0), stream);
  } else {
    run_cheb<3, 32>(x, s0, s1, s2, sc0, enc_w[0], enc_b[0], 20000, 0, RP(0), CS(0), CW(0), stream);
    k_ds<32><<<grid1((long)NB * 5000 * 32), WG, 0, stream>>>(s0, s3, ds_idx[0], 20000, 5000);
    run_cheb<32, 32>(s3, s0, s1, s2, s3, enc_w[1], enc_b[1], 5000, 0, RP(1), CS(1), CW(1), stream);
    k_ds<32><<<grid1((long)NB * 1250 * 32), WG, 0, stream>>>(s0, s3, ds_idx[1], 5000, 1250);
    run_cheb<32, 64>(s3, s0, s1, s2, s3, enc_w[2], enc_b[2], 1250, 0, RP(2), CS(2), CW(2), stream);
    k_ds<64><<<grid1((long)NB * 313 * 64), WG, 0, stream>>>(s0, s3, ds_idx[2], 1250, 313);
    run_cheb<64, 64>(s3, s0, s1, s2, s3, enc_w[3], enc_b[3], 313, 0, RP(3), CS(3), CW(3), stream);
    k_ds<64><<<grid1((long)NB * 79 * 64), WG, 0, stream>>>(s0, s3, ds_idx[3], 313, 79);
    k_latent<<<1024, 64, 0, stream>>>(s3, mu_w, mu_b, lv_w, lv_b, eps, label, mu_out, lv_out, hcat);
    k_declin<<<grid1(NB * 5056), WG, 0, stream>>>(hcat, dl_w, dl_b, s3);
    k_us<64><<<grid1((long)NB * 313 * 64), WG, 0, stream>>>(s3, s1, us_idx[3], us_w[3], 79, 313);
    run_cheb<64, 64>(s1, s0, s2, s3, s1, dec_w[0], dec_b[0], 313, 0, RP(3), CS(3), CW(3), stream);
    k_us<64><<<grid1((long)NB * 1250 * 64), WG, 0, stream>>>(s0, s1, us_idx[2], us_w[2], 313, 1250);
    run_cheb<64, 64>(s1, s0, s2, s3, s1, dec_w[1], dec_b[1], 1250, 0, RP(2), CS(2), CW(2), stream);
    k_us<64><<<grid1((long)NB * 5000 * 64), WG, 0, stream>>>(s0, s1, us_idx[1], us_w[1], 1250, 5000);
    run_cheb<64, 32>(s1, s0, s2, s3, s1, dec_w[2], dec_b[2], 5000, 0, RP(1), CS(1), CW(1), stream);
    k_us<32><<<grid1((long)NB * 20000 * 32), WG, 0, stream>>>(s0, s1, us_idx[0], us_w[0], 5000, 20000);
    run_cheb<32, 32>(s1, s0, s2, s3, s1, dec_w[3], dec_b[3], 20000, 1, RP(0), CS(0), CW(0), stream);
  }

  // ---- final level-4 cheb via shortcut + exact 79-node fixup ----
  k_final_short<<<grid1(NB * 20000), WG, 0, stream>>>(s0, dec_w[4], (float*)d_out, NB * 20000);
  k_final_fix<<<16, 256, 0, stream>>>(s0, dec_w[4], RP(4), CS(4), CW(4), (float*)d_out);
}